// Round 14
// baseline (785.165 us; speedup 1.0000x reference)
//
#include <hip/hip_runtime.h>
#include <cmath>

// Problem constants (fixed by reference): B=8, N=2048, eps=0.01, 50 iters.
#define BATCH 8
#define NPT   2048
#define NPAIR (NPT / 2)               // 1024 column pairs
#define NPTS  (BATCH * NPT)
#define TILES 64                      // blocks per batch; 32 rows each
#define GRID_MAIN 256                 // 4 batch-pairs x 64 tiles; 1 block/CU
#define THREADS 1024                  // 16 waves -> 4/SIMD
#define ITERS 50

// exp(v_j - 100*cost) = exp2( C_LOG2E*v_j + NEG100C*(n_i + n_j) + S200C*dot )
#define C_LOG2E 1.4426950408889634f
#define NEG100C (-144.26950408889634f)   // -100 * log2(e)
#define S200C   288.53900817779268f      //  200 * log2(e)
#define EPS_LOG 1e-8f
#define LN2_01  0.006931471805599453f    // 0.01 * ln(2)

typedef float v2f __attribute__((ext_vector_type(2)));
typedef float v4f __attribute__((ext_vector_type(4)));
typedef unsigned long long u64t;

static __device__ __forceinline__ float fast_exp2(float x) {
#if __has_builtin(__builtin_amdgcn_exp2f)
    return __builtin_amdgcn_exp2f(x);
#else
    return exp2f(x);
#endif
}

// Coherence-point (agent-scope, relaxed) accessors for cross-block data.
static __device__ __forceinline__ float gload(const float* p) {
    return __hip_atomic_load(p, __ATOMIC_RELAXED, __HIP_MEMORY_SCOPE_AGENT);
}
static __device__ __forceinline__ void gstore(float* p, float val) {
    __hip_atomic_store(p, val, __ATOMIC_RELAXED, __HIP_MEMORY_SCOPE_AGENT);
}
static __device__ __forceinline__ u64t gload2(const float* p) {   // 2 floats
    return __hip_atomic_load((const u64t*)p, __ATOMIC_RELAXED,
                             __HIP_MEMORY_SCOPE_AGENT);
}

// ---------------------------------------------------------------------------
__global__ void init_kernel(float* __restrict__ out,
                            unsigned int* __restrict__ flags) {
    int t = threadIdx.x;          // 512 threads
    if (t < BATCH) out[t] = 0.0f;
    flags[t] = 0u;                // BATCH*TILES = 512 flags
}

// ---------------------------------------------------------------------------
// Split flag barrier (R10 machinery — correctness proven).
// arrive: syncthreads drains all waves' stores (incl. wave0 duals), then
//         thread0 stores the phase number to this block's flag.
// wait:   wave0's 64 lanes poll the batch's 64 flags; block-sync after.
// ---------------------------------------------------------------------------
static __device__ __forceinline__ void bar_arrive(unsigned int* flags,
                                                  int slot, unsigned int ph) {
    __syncthreads();
    if (threadIdx.x == 0)
        __hip_atomic_store(&flags[slot], ph, __ATOMIC_RELAXED,
                           __HIP_MEMORY_SCOPE_AGENT);
}
static __device__ __forceinline__ void bar_wait(const unsigned int* bf,
                                                int wave, int lane,
                                                unsigned int ph) {
    if (wave == 0) {
        while (__hip_atomic_load(&bf[lane], __ATOMIC_RELAXED,
                                 __HIP_MEMORY_SCOPE_AGENT) < ph) {
            __builtin_amdgcn_s_sleep(1);
        }
    }
    __syncthreads();
    __builtin_amdgcn_sched_barrier(0);
}

// ---------------------------------------------------------------------------
// 2-rows-per-lane half-pass core on a 32-row tile: lane owns rows (rloc,
// rloc+16); columns stream quarter-wave-uniform, chunk-interleaved
// (pair = wave*64 + 4s + ch) so the 4 addrs/instr hit 16 distinct banks.
// Per wave: 32 ds_read_b128 per phase (R12's ratio: 16B per 4 exps).
// ---------------------------------------------------------------------------
static __device__ __forceinline__ v2f half_core2(
        const v4f* cdXY, const v4f* cdZW, int p0,
        const v2f (&RX)[2], const v2f (&RY)[2],
        const v2f (&RZ)[2], const v2f (&RC)[2])
{
    v2f a0 = {0.0f, 0.0f}, a1 = {0.0f, 0.0f};
#pragma unroll 4
    for (int s = 0; s < 16; s++) {
        v4f A = cdXY[p0 + 4 * s];                  // quarter-uniform b128
        v4f B = cdZW[p0 + 4 * s];
        v2f xx = __builtin_shufflevector(A, A, 0, 1);
        v2f yy = __builtin_shufflevector(A, A, 2, 3);
        v2f zz = __builtin_shufflevector(B, B, 0, 1);
        v2f ww = __builtin_shufflevector(B, B, 2, 3);
        v2f t0 = xx * RX[0] + ww;                  // compiler emits v_pk_fma
        t0 = yy * RY[0] + t0;
        t0 = zz * RZ[0] + t0;
        t0 = t0 + RC[0];
        v2f t1 = xx * RX[1] + ww;
        t1 = yy * RY[1] + t1;
        t1 = zz * RZ[1] + t1;
        t1 = t1 + RC[1];
        a0.x += fast_exp2(t0.x);
        a0.y += fast_exp2(t0.y);
        a1.x += fast_exp2(t1.x);
        a1.y += fast_exp2(t1.y);
    }
    return (v2f){a0.x + a0.y, a1.x + a1.y};
}

// ---------------------------------------------------------------------------
// Dual-batch software-pipelined persistent kernel with the R12 LDS-efficient
// core: every wait(X) is separated from arrive(X) by a full compute phase of
// the other batch -> barrier propagation hidden.
// LDS = 128KB tiles + 2.5KB pad -> 1 block/CU, 16 waves = 4/SIMD.
// ---------------------------------------------------------------------------
__global__ __launch_bounds__(THREADS, 4) void sinkhorn_kernel(
        const float* __restrict__ x1, const float* __restrict__ x2,
        float* __restrict__ u, float* __restrict__ v,
        unsigned int* __restrict__ flags, float* __restrict__ out)
{
    __shared__ v4f c1XY[2][NPAIR], c1ZW[2][NPAIR];   // side-1 (dual = u)
    __shared__ v4f c2XY[2][NPAIR], c2ZW[2][NPAIR];   // side-2 (dual = v)
    __shared__ __align__(16) float part[32][20];     // cross-wave reduce pad

    const int b0   = blockIdx.x / TILES;      // 0..3
    const int tile = blockIdx.x % TILES;
    const int bA = b0, bB = b0 + 4;
    const int baseA = bA * NPT, baseB = bB * NPT;
    const int slotA = bA * TILES + tile, slotB = bB * TILES + tile;
    const unsigned int* flA = flags + bA * TILES;
    const unsigned int* flB = flags + bB * TILES;

    const int tid  = threadIdx.x;
    const int wave = tid >> 6;
    const int lane = tid & 63;
    const int rloc = lane & 15;              // rows rloc, rloc+16
    const int ch   = lane >> 4;              // column chunk 0..3 (interleaved)
    const int p0   = wave * 64 + ch;         // this lane's pair base

    const float log_mu = logf(1.0f / (float)NPT + EPS_LOG);   // == log_nu

    // ---- one-time staging: thread t stages pair t, both batches/sides ----
    float P1a[2], P1b[2], P2a[2], P2b[2];
#pragma unroll
    for (int g = 0; g < 2; g++) {
        int base = g ? baseB : baseA;
        const float* p = x1 + 3 * (base + 2 * tid);
        float ax = p[0], ay = p[1], az = p[2];
        float bx = p[3], by = p[4], bz = p[5];
        float na = fmaf(ax, ax, fmaf(ay, ay, az * az));
        float nb = fmaf(bx, bx, fmaf(by, by, bz * bz));
        P1a[g] = na * NEG100C;  P1b[g] = nb * NEG100C;
        c1XY[g][tid] = (v4f){ax * S200C, bx * S200C, ay * S200C, by * S200C};
        c1ZW[g][tid] = (v4f){az * S200C, bz * S200C, P1a[g], P1b[g]};

        p = x2 + 3 * (base + 2 * tid);
        ax = p[0]; ay = p[1]; az = p[2];
        bx = p[3]; by = p[4]; bz = p[5];
        na = fmaf(ax, ax, fmaf(ay, ay, az * az));
        nb = fmaf(bx, bx, fmaf(by, by, bz * bz));
        P2a[g] = na * NEG100C;  P2b[g] = nb * NEG100C;
        c2XY[g][tid] = (v4f){ax * S200C, bx * S200C, ay * S200C, by * S200C};
        c2ZW[g][tid] = (v4f){az * S200C, bz * S200C, P2a[g], P2b[g]};
    }

    // ---- lane's TWO-row constants per batch (splatted), both sides ----
    v2f RX1[2][2], RY1[2][2], RZ1[2][2], RC1[2][2];
    v2f RX2[2][2], RY2[2][2], RZ2[2][2], RC2[2][2];
    float rc1s[2][2];
#pragma unroll
    for (int g = 0; g < 2; g++) {
        int base = g ? baseB : baseA;
#pragma unroll
        for (int rr = 0; rr < 2; rr++) {
            int row = tile * 32 + rloc + 16 * rr;
            const float* p = x1 + 3 * (base + row);
            float a = p[0], bb = p[1], c = p[2];
            float nn = NEG100C * fmaf(a, a, fmaf(bb, bb, c * c));
            RX1[g][rr] = (v2f){a, a};  RY1[g][rr] = (v2f){bb, bb};
            RZ1[g][rr] = (v2f){c, c};  RC1[g][rr] = (v2f){nn, nn};
            rc1s[g][rr] = nn;
            p = x2 + 3 * (base + row);
            a = p[0]; bb = p[1]; c = p[2];
            nn = NEG100C * fmaf(a, a, fmaf(bb, bb, c * c));
            RX2[g][rr] = (v2f){a, a};  RY2[g][rr] = (v2f){bb, bb};
            RZ2[g][rr] = (v2f){c, c};  RC2[g][rr] = (v2f){nn, nn};
        }
    }
    __syncthreads();

    // ---- helpers ----
    // One phase: compute 32 rows x 2048 cols, one syncthreads, wave0 reduce
    // + coalesced dual store. (Caller issues bar_arrive right after.)
    auto do_phase = [&](const v4f* XY, const v4f* ZW,
                        const v2f (&RX)[2], const v2f (&RY)[2],
                        const v2f (&RZ)[2], const v2f (&RC)[2],
                        float* drow) {
        v2f s2 = half_core2(XY, ZW, p0, RX, RY, RZ, RC);
        s2.x += __shfl_xor(s2.x, 16, 64);        // combine 4 column chunks
        s2.x += __shfl_xor(s2.x, 32, 64);
        s2.y += __shfl_xor(s2.y, 16, 64);
        s2.y += __shfl_xor(s2.y, 32, 64);
        if (lane < 16) {
            part[rloc][wave]      = s2.x;
            part[rloc + 16][wave] = s2.y;
        }
        __syncthreads();
        if (wave == 0 && lane < 32) {             // lane = row 0..31
            const v4f* pr = reinterpret_cast<const v4f*>(&part[lane][0]);
            v4f q0 = pr[0], q1 = pr[1], q2 = pr[2], q3 = pr[3];
            float t = ((q0.x + q0.y) + (q0.z + q0.w)) +
                      ((q1.x + q1.y) + (q1.z + q1.w)) +
                      ((q2.x + q2.y) + (q2.z + q2.w)) +
                      ((q3.x + q3.y) + (q3.z + q3.w));
            gstore(drow + lane, log_mu - __logf(t + EPS_LOG));  // coalesced
        }
    };
    // Wave-self-contained folds: thread t refreshes w-slot of pair t (inside
    // its own wave's read span [64w,64w+64)); no extra barrier needed.
    auto fold_u = [&](int g) {
        u64t d = gload2(u + (g ? baseB : baseA) + 2 * tid);
        reinterpret_cast<v2f*>(&c1ZW[g][tid])[1] = (v2f){
            fmaf(C_LOG2E, __uint_as_float((unsigned)d), P1a[g]),
            fmaf(C_LOG2E, __uint_as_float((unsigned)(d >> 32)), P1b[g])};
    };
    auto fold_v = [&](int g) {
        u64t d = gload2(v + (g ? baseB : baseA) + 2 * tid);
        reinterpret_cast<v2f*>(&c2ZW[g][tid])[1] = (v2f){
            fmaf(C_LOG2E, __uint_as_float((unsigned)d), P2a[g]),
            fmaf(C_LOG2E, __uint_as_float((unsigned)(d >> 32)), P2b[g])};
    };

    float* uA = u + baseA + tile * 32;  float* uB = u + baseB + tile * 32;
    float* vA = v + baseA + tile * 32;  float* vB = v + baseB + tile * 32;

    // ---- software-pipelined 50 iterations ----
    // prologue: iter-0 u-phases (v=0 -> w=P already staged)
    do_phase(c2XY[0], c2ZW[0], RX1[0], RY1[0], RZ1[0], RC1[0], uA);
    bar_arrive(flags, slotA, 1);
    do_phase(c2XY[1], c2ZW[1], RX1[1], RY1[1], RZ1[1], RC1[1], uB);
    bar_arrive(flags, slotB, 1);

    for (int it = 0; it < ITERS; it++) {
        const unsigned pu = 2 * it + 1, pv = 2 * it + 2;
        bar_wait(flA, wave, lane, pu);           // uB propagates under vA
        fold_u(0);
        do_phase(c1XY[0], c1ZW[0], RX2[0], RY2[0], RZ2[0], RC2[0], vA);
        bar_arrive(flags, slotA, pv);
        bar_wait(flB, wave, lane, pu);           // vA propagates under vB
        fold_u(1);
        do_phase(c1XY[1], c1ZW[1], RX2[1], RY2[1], RZ2[1], RC2[1], vB);
        bar_arrive(flags, slotB, pv);
        if (it < ITERS - 1) {
            bar_wait(flA, wave, lane, pv);       // vB propagates under uA'
            fold_v(0);
            do_phase(c2XY[0], c2ZW[0], RX1[0], RY1[0], RZ1[0], RC1[0], uA);
            bar_arrive(flags, slotA, pu + 2);
            bar_wait(flB, wave, lane, pv);       // uA' propagates into next it
            fold_v(1);
            do_phase(c2XY[1], c2ZW[1], RX1[1], RY1[1], RZ1[1], RC1[1], uB);
            bar_arrive(flags, slotB, pu + 2);
        }
    }
    bar_wait(flA, wave, lane, 2 * ITERS);        // final v complete (exposed
    bar_wait(flB, wave, lane, 2 * ITERS);        // once; negligible)

    // ---- fused EMD epilogue (both batches):
    //      cost = 0.01*(u_i+v_j) - 0.01*ln2 * t  (algebraically exact) ----
    v2f* cvp0 = reinterpret_cast<v2f*>(c1XY[0]);   // reused, no other reader
    v2f* cvp1 = reinterpret_cast<v2f*>(c1XY[1]);
    {
        u64t dA = gload2(v + baseA + 2 * tid);
        u64t dB = gload2(v + baseB + 2 * tid);
        float aA = __uint_as_float((unsigned)dA);
        float bA2 = __uint_as_float((unsigned)(dA >> 32));
        float aB = __uint_as_float((unsigned)dB);
        float bB2 = __uint_as_float((unsigned)(dB >> 32));
        reinterpret_cast<v2f*>(&c2ZW[0][tid])[1] =
            (v2f){fmaf(C_LOG2E, aA, P2a[0]), fmaf(C_LOG2E, bA2, P2b[0])};
        reinterpret_cast<v2f*>(&c2ZW[1][tid])[1] =
            (v2f){fmaf(C_LOG2E, aB, P2a[1]), fmaf(C_LOG2E, bB2, P2b[1])};
        cvp0[tid] = (v2f){0.01f * aA, 0.01f * bA2};
        cvp1[tid] = (v2f){0.01f * aB, 0.01f * bB2};
    }
    __syncthreads();

    const v2f NL2 = {-LN2_01, -LN2_01};
    float es[2];
#pragma unroll
    for (int g = 0; g < 2; g++) {
        int base = g ? baseB : baseA;
        v2f* cvp = g ? cvp1 : cvp0;
        float ur0 = gload(&u[base + tile * 32 + rloc]);
        float ur1 = gload(&u[base + tile * 32 + rloc + 16]);
        float r0 = fmaf(C_LOG2E, ur0, rc1s[g][0]);
        float r1 = fmaf(C_LOG2E, ur1, rc1s[g][1]);
        v2f RCC0 = (v2f){r0, r0}, RCC1 = (v2f){r1, r1};
        v2f SU0 = (v2f){0.01f * ur0, 0.01f * ur0};
        v2f SU1 = (v2f){0.01f * ur1, 0.01f * ur1};
        v2f e0 = {0.0f, 0.0f}, e1 = {0.0f, 0.0f};
#pragma unroll 4
        for (int s = 0; s < 16; s++) {
            v4f A   = c2XY[g][p0 + 4 * s];
            v4f B   = c2ZW[g][p0 + 4 * s];
            v2f cv2 = cvp[p0 + 4 * s];
            v2f xx = __builtin_shufflevector(A, A, 0, 1);
            v2f yy = __builtin_shufflevector(A, A, 2, 3);
            v2f zz = __builtin_shufflevector(B, B, 0, 1);
            v2f ww = __builtin_shufflevector(B, B, 2, 3);
            v2f t0 = xx * RX1[g][0] + ww;
            t0 = yy * RY1[g][0] + t0;
            t0 = zz * RZ1[g][0] + t0;
            t0 = t0 + RCC0;
            v2f c20 = t0 * NL2 + (SU0 + cv2);
            e0.x = fmaf(fast_exp2(t0.x), c20.x, e0.x);
            e0.y = fmaf(fast_exp2(t0.y), c20.y, e0.y);
            v2f t1 = xx * RX1[g][1] + ww;
            t1 = yy * RY1[g][1] + t1;
            t1 = zz * RZ1[g][1] + t1;
            t1 = t1 + RCC1;
            v2f c21 = t1 * NL2 + (SU1 + cv2);
            e1.x = fmaf(fast_exp2(t1.x), c21.x, e1.x);
            e1.y = fmaf(fast_exp2(t1.y), c21.y, e1.y);
        }
        float e = (e0.x + e0.y) + (e1.x + e1.y);
#pragma unroll
        for (int m = 32; m >= 1; m >>= 1) e += __shfl_xor(e, m, 64);
        es[g] = e;
    }

    if (lane == 0) { part[0][wave] = es[0]; part[1][wave] = es[1]; }
    __syncthreads();
    if (tid == 0) {
        float sA = 0.0f, sB = 0.0f;
#pragma unroll
        for (int w = 0; w < 16; w++) { sA += part[0][w]; sB += part[1][w]; }
        atomicAdd(&out[bA], sA);
        atomicAdd(&out[bB], sB);
    }
}

// ---------------------------------------------------------------------------
extern "C" void kernel_launch(void* const* d_in, const int* in_sizes, int n_in,
                              void* d_out, int out_size, void* d_ws, size_t ws_size,
                              hipStream_t stream) {
    (void)in_sizes; (void)n_in; (void)out_size; (void)ws_size;
    const float* x1 = (const float*)d_in[0];
    const float* x2 = (const float*)d_in[1];
    float* out = (float*)d_out;

    char* ws = (char*)d_ws;
    float* u = (float*)ws;                             // NPTS floats
    float* v = u + NPTS;                               // NPTS floats
    unsigned int* flags = (unsigned int*)(v + NPTS);   // BATCH*TILES uints

    init_kernel<<<1, 512, 0, stream>>>(out, flags);
    sinkhorn_kernel<<<GRID_MAIN, THREADS, 0, stream>>>(x1, x2, u, v, flags, out);
}

// Round 15
// 675.938 us; speedup vs baseline: 1.1616x; 1.1616x over previous
//
#include <hip/hip_runtime.h>
#include <cmath>

// Problem constants (fixed by reference): B=8, N=2048, eps=0.01, 50 iters.
#define BATCH 8
#define NPT   2048
#define NPAIR (NPT / 2)               // 1024 column pairs
#define NPTS  (BATCH * NPT)
#define TILES 32                      // blocks per batch (64 rows each)
#define GRID_MAIN (BATCH * TILES)     // 256 blocks; ~83KB LDS -> 1 block/CU
#define THREADS 1024                  // 16 waves -> 4/SIMD
#define ITERS 50

// exp(v_j - 100*cost) = exp2( C_LOG2E*v_j + NEG100C*(n_i + n_j) + S200C*dot )
#define C_LOG2E 1.4426950408889634f
#define NEG100C (-144.26950408889634f)   // -100 * log2(e)
#define S200C   288.53900817779268f      //  200 * log2(e)
#define EPS_LOG 1e-8f
#define LN2_01  0.006931471805599453f    // 0.01 * ln(2)

typedef float v2f __attribute__((ext_vector_type(2)));
typedef float v4f __attribute__((ext_vector_type(4)));
typedef unsigned long long u64t;

static __device__ __forceinline__ float fast_exp2(float x) {
#if __has_builtin(__builtin_amdgcn_exp2f)
    return __builtin_amdgcn_exp2f(x);
#else
    return exp2f(x);
#endif
}

// Coherence-point (agent-scope, relaxed) accessors for cross-block data.
static __device__ __forceinline__ float gload(const float* p) {
    return __hip_atomic_load(p, __ATOMIC_RELAXED, __HIP_MEMORY_SCOPE_AGENT);
}
static __device__ __forceinline__ void gstore(float* p, float val) {
    __hip_atomic_store(p, val, __ATOMIC_RELAXED, __HIP_MEMORY_SCOPE_AGENT);
}
static __device__ __forceinline__ u64t gload2(const float* p) {   // 2 floats
    return __hip_atomic_load((const u64t*)p, __ATOMIC_RELAXED,
                             __HIP_MEMORY_SCOPE_AGENT);
}

// ---------------------------------------------------------------------------
__global__ void init_kernel(float* __restrict__ out,
                            unsigned int* __restrict__ flags) {
    int t = threadIdx.x;          // 256 threads
    if (t < BATCH) out[t] = 0.0f;
    flags[t] = 0u;                // BATCH*TILES = 256 flags
}

// ---------------------------------------------------------------------------
// Flag-array barrier — R8-proven machinery (TILES=32-wide poll).
// ---------------------------------------------------------------------------
static __device__ __forceinline__ void flag_barrier(unsigned int* bflags,
                                                    int tile, int wave,
                                                    int lane,
                                                    unsigned int phase) {
    __syncthreads();
    if (wave == 0) {
        if (lane == 0)
            __hip_atomic_store(&bflags[tile], phase, __ATOMIC_RELAXED,
                               __HIP_MEMORY_SCOPE_AGENT);
        if (lane < TILES) {
            while (__hip_atomic_load(&bflags[lane], __ATOMIC_RELAXED,
                                     __HIP_MEMORY_SCOPE_AGENT) < phase) {
                __builtin_amdgcn_s_sleep(1);
            }
        }
    }
    __syncthreads();
    __builtin_amdgcn_sched_barrier(0);
}

// ---------------------------------------------------------------------------
// 2-rows-per-lane half-pass core: lane owns TWO rows (rloc, rloc+32); each
// 32B pair fill (2 half-wave-uniform b128) feeds 4 exps -> LDS instruction
// count halved vs 1-row/lane. Columns stream half-wave-uniform.
// Returns (partial_row0, partial_row1) over this lane's 32 pairs (64 cols).
// ---------------------------------------------------------------------------
static __device__ __forceinline__ v2f half_core2(
        const v4f* cdXY, const v4f* cdZW, int p0,
        const v2f (&RX)[2], const v2f (&RY)[2],
        const v2f (&RZ)[2], const v2f (&RC)[2])
{
    v2f a0 = {0.0f, 0.0f}, a1 = {0.0f, 0.0f};
#pragma unroll 4
    for (int s = 0; s < 32; s++) {
        v4f A = cdXY[p0 + s];                      // uniform ds_read_b128
        v4f B = cdZW[p0 + s];                      // uniform ds_read_b128
        v2f xx = __builtin_shufflevector(A, A, 0, 1);
        v2f yy = __builtin_shufflevector(A, A, 2, 3);
        v2f zz = __builtin_shufflevector(B, B, 0, 1);
        v2f ww = __builtin_shufflevector(B, B, 2, 3);
        v2f t0 = xx * RX[0] + ww;                  // compiler emits v_pk_fma
        t0 = yy * RY[0] + t0;
        t0 = zz * RZ[0] + t0;
        t0 = t0 + RC[0];
        v2f t1 = xx * RX[1] + ww;
        t1 = yy * RY[1] + t1;
        t1 = zz * RZ[1] + t1;
        t1 = t1 + RC[1];
        a0.x += fast_exp2(t0.x);
        a0.y += fast_exp2(t0.y);
        a1.x += fast_exp2(t1.x);
        a1.y += fast_exp2(t1.y);
    }
    return (v2f){a0.x + a0.y, a1.x + a1.y};
}

// ---------------------------------------------------------------------------
// Persistent kernel, 64 rows/block, 2 rows/lane.
// LDS = 64KB tiles + 17.4KB part = ~83KB -> exactly 1 block/CU (forced),
// 16 waves = 4/SIMD. Best measured configuration (R12: 676us).
// ---------------------------------------------------------------------------
__global__ __launch_bounds__(THREADS, 4) void sinkhorn_kernel(
        const float* __restrict__ x1, const float* __restrict__ x2,
        float* __restrict__ u, float* __restrict__ v,
        unsigned int* __restrict__ flags, float* __restrict__ out)
{
    __shared__ v4f cd1XY[NPAIR], cd1ZW[NPAIR];   // side-1 cols (dual = u)
    __shared__ v4f cd2XY[NPAIR], cd2ZW[NPAIR];   // side-2 cols (dual = v)
    __shared__ __align__(16) float part[64][68]; // 16B-aligned rows, 17.4KB

    const int b    = blockIdx.x / TILES;
    const int tile = blockIdx.x % TILES;
    const int base = b * NPT;
    unsigned int* bflags = flags + b * TILES;

    const int tid  = threadIdx.x;
    const int wave = tid >> 6;
    const int lane = tid & 63;
    const int rloc = lane & 31;              // local row 0..31 (rows rloc, rloc+32)
    const int ch   = lane >> 5;              // column half of wave's span
    const int p0   = wave * 64 + ch * 32;    // this lane's pair base (32 pairs)

    const float log_mu = logf(1.0f / (float)NPT + EPS_LOG);   // == log_nu

    // ---- one-time staging: thread t stages pair t (both sides) ----
    float P1a, P1b, P2a, P2b;
    {
        const float* p = x1 + 3 * (base + 2 * tid);
        float ax = p[0], ay = p[1], az = p[2];
        float bx = p[3], by = p[4], bz = p[5];
        float na = fmaf(ax, ax, fmaf(ay, ay, az * az));
        float nb = fmaf(bx, bx, fmaf(by, by, bz * bz));
        P1a = na * NEG100C;  P1b = nb * NEG100C;
        cd1XY[tid] = (v4f){ax * S200C, bx * S200C, ay * S200C, by * S200C};
        cd1ZW[tid] = (v4f){az * S200C, bz * S200C, P1a, P1b};

        p = x2 + 3 * (base + 2 * tid);
        ax = p[0]; ay = p[1]; az = p[2];
        bx = p[3]; by = p[4]; bz = p[5];
        na = fmaf(ax, ax, fmaf(ay, ay, az * az));
        nb = fmaf(bx, bx, fmaf(by, by, bz * bz));
        P2a = na * NEG100C;  P2b = nb * NEG100C;
        cd2XY[tid] = (v4f){ax * S200C, bx * S200C, ay * S200C, by * S200C};
        cd2ZW[tid] = (v4f){az * S200C, bz * S200C, P2a, P2b};
    }

    // ---- lane's TWO-row constants (splatted), both sides ----
    v2f RX1[2], RY1[2], RZ1[2], RC1[2], RX2[2], RY2[2], RZ2[2], RC2[2];
    float rc1s[2];
#pragma unroll
    for (int rr = 0; rr < 2; rr++) {
        int row = tile * 64 + rloc + 32 * rr;
        const float* p = x1 + 3 * (base + row);
        float a = p[0], bb = p[1], c = p[2];
        float nn = NEG100C * fmaf(a, a, fmaf(bb, bb, c * c));
        RX1[rr] = (v2f){a, a};  RY1[rr] = (v2f){bb, bb};
        RZ1[rr] = (v2f){c, c};  RC1[rr] = (v2f){nn, nn};
        rc1s[rr] = nn;
        p = x2 + 3 * (base + row);
        a = p[0]; bb = p[1]; c = p[2];
        nn = NEG100C * fmaf(a, a, fmaf(bb, bb, c * c));
        RX2[rr] = (v2f){a, a};  RY2[rr] = (v2f){bb, bb};
        RZ2[rr] = (v2f){c, c};  RC2[rr] = (v2f){nn, nn};
    }
    __syncthreads();

    // ---- helpers ----
    // Wave-self-contained fold: thread t refreshes the w-slot of pair t
    // (exactly within its wave's read span [64w,64w+64)); no barrier needed.
    auto fold2 = [&](v4f* ZW, const float* dual, float Pa, float Pb) {
        u64t d = gload2(dual + base + 2 * tid);
        reinterpret_cast<v2f*>(&ZW[tid])[1] = (v2f){
            fmaf(C_LOG2E, __uint_as_float((unsigned)d), Pa),
            fmaf(C_LOG2E, __uint_as_float((unsigned)(d >> 32)), Pb)};
    };
    auto do_phase = [&](const v4f* XY, const v4f* ZW,
                        const v2f (&RX)[2], const v2f (&RY)[2],
                        const v2f (&RZ)[2], const v2f (&RC)[2],
                        float* drow, unsigned int php) {
        v2f s2 = half_core2(XY, ZW, p0, RX, RY, RZ, RC);
        s2.x += __shfl_xor(s2.x, 32, 64);        // combine column halves
        s2.y += __shfl_xor(s2.y, 32, 64);
        if (lane < 32) {
            part[rloc][wave]      = s2.x;
            part[rloc + 32][wave] = s2.y;
        }
        __syncthreads();
        if (wave == 0) {                          // lane = row 0..63
            const v4f* pr = reinterpret_cast<const v4f*>(&part[lane][0]);
            v4f q0 = pr[0], q1 = pr[1], q2 = pr[2], q3 = pr[3];
            float t = ((q0.x + q0.y) + (q0.z + q0.w)) +
                      ((q1.x + q1.y) + (q1.z + q1.w)) +
                      ((q2.x + q2.y) + (q2.z + q2.w)) +
                      ((q3.x + q3.y) + (q3.z + q3.w));
            gstore(drow + lane, log_mu - __logf(t + EPS_LOG));  // coalesced
        }
        flag_barrier(bflags, tile, wave, lane, php);
    };

    float* urow = u + base + tile * 64;
    float* vrow = v + base + tile * 64;

    // ---- 50 iterations, phases 1..100 ----
    do_phase(cd2XY, cd2ZW, RX1, RY1, RZ1, RC1, urow, 1);   // iter0 u (v=0)
    for (int it = 0; it < ITERS; it++) {
        fold2(cd1ZW, u, P1a, P1b);                         // fresh u -> side1 w
        do_phase(cd1XY, cd1ZW, RX2, RY2, RZ2, RC2, vrow, 2 * it + 2);
        if (it < ITERS - 1) {
            fold2(cd2ZW, v, P2a, P2b);                     // fresh v -> side2 w
            do_phase(cd2XY, cd2ZW, RX1, RY1, RZ1, RC1, urow, 2 * it + 3);
        }
    }

    // ---- fused EMD epilogue: emd[b] = sum_ij exp2(t) * cost,
    //      cost = 0.01*(u_i+v_j) - 0.01*ln2 * t  (algebraically exact) ----
    v2f* cvp = reinterpret_cast<v2f*>(cd1XY);   // wave-own-span reuse only
    {
        u64t d = gload2(v + base + 2 * tid);
        float a0 = __uint_as_float((unsigned)d);
        float b0 = __uint_as_float((unsigned)(d >> 32));
        reinterpret_cast<v2f*>(&cd2ZW[tid])[1] =
            (v2f){fmaf(C_LOG2E, a0, P2a), fmaf(C_LOG2E, b0, P2b)};
        cvp[tid] = (v2f){0.01f * a0, 0.01f * b0};
    }
    __syncthreads();

    float ur0 = gload(&u[base + tile * 64 + rloc]);
    float ur1 = gload(&u[base + tile * 64 + rloc + 32]);
    v2f RCC0 = (v2f){fmaf(C_LOG2E, ur0, rc1s[0]), fmaf(C_LOG2E, ur0, rc1s[0])};
    v2f RCC1 = (v2f){fmaf(C_LOG2E, ur1, rc1s[1]), fmaf(C_LOG2E, ur1, rc1s[1])};
    v2f SU0 = (v2f){0.01f * ur0, 0.01f * ur0};
    v2f SU1 = (v2f){0.01f * ur1, 0.01f * ur1};

    const v2f NL2 = {-LN2_01, -LN2_01};
    v2f e0 = {0.0f, 0.0f}, e1 = {0.0f, 0.0f};
#pragma unroll 4
    for (int s = 0; s < 32; s++) {
        v4f A  = cd2XY[p0 + s];
        v4f B  = cd2ZW[p0 + s];
        v2f cv2 = cvp[p0 + s];
        v2f xx = __builtin_shufflevector(A, A, 0, 1);
        v2f yy = __builtin_shufflevector(A, A, 2, 3);
        v2f zz = __builtin_shufflevector(B, B, 0, 1);
        v2f ww = __builtin_shufflevector(B, B, 2, 3);
        v2f t0 = xx * RX1[0] + ww;
        t0 = yy * RY1[0] + t0;
        t0 = zz * RZ1[0] + t0;
        t0 = t0 + RCC0;
        v2f c20 = t0 * NL2 + (SU0 + cv2);
        e0.x = fmaf(fast_exp2(t0.x), c20.x, e0.x);
        e0.y = fmaf(fast_exp2(t0.y), c20.y, e0.y);
        v2f t1 = xx * RX1[1] + ww;
        t1 = yy * RY1[1] + t1;
        t1 = zz * RZ1[1] + t1;
        t1 = t1 + RCC1;
        v2f c21 = t1 * NL2 + (SU1 + cv2);
        e1.x = fmaf(fast_exp2(t1.x), c21.x, e1.x);
        e1.y = fmaf(fast_exp2(t1.y), c21.y, e1.y);
    }
    float es = (e0.x + e0.y) + (e1.x + e1.y);
#pragma unroll
    for (int m = 32; m >= 1; m >>= 1) es += __shfl_xor(es, m, 64);

    if (lane == 0) part[0][wave] = es;
    __syncthreads();
    if (tid == 0) {
        float s = 0.0f;
#pragma unroll
        for (int w = 0; w < 16; w++) s += part[0][w];
        atomicAdd(&out[b], s);
    }
}

// ---------------------------------------------------------------------------
extern "C" void kernel_launch(void* const* d_in, const int* in_sizes, int n_in,
                              void* d_out, int out_size, void* d_ws, size_t ws_size,
                              hipStream_t stream) {
    (void)in_sizes; (void)n_in; (void)out_size; (void)ws_size;
    const float* x1 = (const float*)d_in[0];
    const float* x2 = (const float*)d_in[1];
    float* out = (float*)d_out;

    char* ws = (char*)d_ws;
    float* u = (float*)ws;                             // NPTS floats
    float* v = u + NPTS;                               // NPTS floats
    unsigned int* flags = (unsigned int*)(v + NPTS);   // BATCH*TILES uints

    init_kernel<<<1, 256, 0, stream>>>(out, flags);
    sinkhorn_kernel<<<GRID_MAIN, THREADS, 0, stream>>>(x1, x2, u, v, flags, out);
}